// Round 1
// baseline (2071.434 us; speedup 1.0000x reference)
//
#include <hip/hip_runtime.h>
#include <math.h>

#define NN 50     // neighbours
#define DD 128    // embedding dim

// Precomputed W@A1 and W@A2 (each [D][D] fp32, 64 KB). __device__ globals so we
// don't depend on ws_size; rewritten deterministically every launch.
__device__ float g_WA1[DD * DD];
__device__ float g_WA2[DD * DD];

// WA_m[k][d] = sum_j W[k][j] * A_w[m*D + j][d]
__global__ void precompute_wa(const float* __restrict__ W,
                              const float* __restrict__ A_w) {
    const int d = threadIdx.x;   // 0..127
    const int k = blockIdx.x;    // 0..127
    const int m = blockIdx.y;    // 0: A1, 1: A2
    const float* __restrict__ A = A_w + (size_t)m * DD * DD;
    float acc = 0.f;
#pragma unroll 8
    for (int j = 0; j < DD; ++j)
        acc = fmaf(W[k * DD + j], A[j * DD + d], acc);
    if (m == 0) g_WA1[k * DD + d] = acc;
    else        g_WA2[k * DD + d] = acc;
}

// One block per batch element. 256 threads: d = tid&127 (output channel),
// half = tid>>7 (rows 0..24 vs 25..49). Each thread accumulates
// pn[n][d] and s[n][d] for its 25 rows; softmax is register-local except
// a 2-way exchange between halves via LDS.
__global__ __launch_bounds__(256, 4)
void attn_main(const float* __restrict__ x,
               const float* __restrict__ nbr,
               const float* __restrict__ W,
               const float* __restrict__ A_b,
               float* __restrict__ out) {
    __shared__ float4 nbr_s4[NN * DD / 4];   // 25.6 KB
    __shared__ float  x_s[DD];
    __shared__ float  pxA_s[DD];
    __shared__ float  red_a[2][DD];
    __shared__ float  red_b[2][DD];

    const int b    = blockIdx.x;
    const int tid  = threadIdx.x;
    const int d    = tid & (DD - 1);
    const int half = tid >> 7;

    if (tid < DD) x_s[tid] = x[(size_t)b * DD + tid];
    {
        const float4* __restrict__ g4 =
            reinterpret_cast<const float4*>(nbr + (size_t)b * NN * DD);
#pragma unroll
        for (int i = 0; i < 7; ++i) {
            const int idx = tid + i * 256;
            if (idx < NN * DD / 4) nbr_s4[idx] = g4[idx];
        }
    }
    __syncthreads();

    // pxA[d] = A_b[d] + sum_k x[k] * WA1[k][d], split across halves.
    {
        float acc = half ? 0.f : A_b[d];
        const int k0 = half * (DD / 2);
#pragma unroll 8
        for (int kk = 0; kk < DD / 2; ++kk) {
            const int k = k0 + kk;
            acc = fmaf(x_s[k], g_WA1[k * DD + d], acc);
        }
        red_a[half][d] = acc;
    }

    // Main: acc_pn[i] = pn[n0+i][d], acc_s[i] = (nbr@WA2)[n0+i][d]
    const int n0 = half * (NN / 2);
    float acc_pn[NN / 2];
    float acc_s[NN / 2];
#pragma unroll
    for (int i = 0; i < NN / 2; ++i) { acc_pn[i] = 0.f; acc_s[i] = 0.f; }

#pragma unroll 2
    for (int k4 = 0; k4 < DD / 4; ++k4) {
        const int kb = k4 * 4;
        // W / WA2 column slices: 64 consecutive d per wave -> coalesced, L1-hot.
        const float w0 = W[(kb + 0) * DD + d];
        const float w1 = W[(kb + 1) * DD + d];
        const float w2 = W[(kb + 2) * DD + d];
        const float w3 = W[(kb + 3) * DD + d];
        const float u0 = g_WA2[(kb + 0) * DD + d];
        const float u1 = g_WA2[(kb + 1) * DD + d];
        const float u2 = g_WA2[(kb + 2) * DD + d];
        const float u3 = g_WA2[(kb + 3) * DD + d];
#pragma unroll
        for (int i = 0; i < NN / 2; ++i) {
            // same address across the wave -> LDS broadcast, conflict-free
            const float4 a = nbr_s4[(n0 + i) * (DD / 4) + k4];
            float p = acc_pn[i], s = acc_s[i];
            p = fmaf(a.x, w0, p); s = fmaf(a.x, u0, s);
            p = fmaf(a.y, w1, p); s = fmaf(a.y, u1, s);
            p = fmaf(a.z, w2, p); s = fmaf(a.z, u2, s);
            p = fmaf(a.w, w3, p); s = fmaf(a.w, u3, s);
            acc_pn[i] = p; acc_s[i] = s;
        }
    }

    __syncthreads();                       // pxA partials in red_a visible
    if (half == 0) pxA_s[d] = red_a[0][d] + red_a[1][d];
    __syncthreads();                       // pxA_s visible (red_a reads done)

    // e = leaky_relu(pxA + s), running max (overwrite acc_s with e)
    const float pxa = pxA_s[d];
    float m = -3.4e38f;
#pragma unroll
    for (int i = 0; i < NN / 2; ++i) {
        float v = pxa + acc_s[i];
        v = v > 0.f ? v : 0.2f * v;        // leaky_relu alpha = 0.2
        acc_s[i] = v;
        m = fmaxf(m, v);
    }
    red_a[half][d] = m;
    __syncthreads();
    m = fmaxf(red_a[0][d], red_a[1][d]);

    float se = 0.f, sw = 0.f;
#pragma unroll
    for (int i = 0; i < NN / 2; ++i) {
        const float p = __expf(acc_s[i] - m);
        se += p;
        sw = fmaf(p, acc_pn[i], sw);
    }
    __syncthreads();                       // everyone done reading red_a maxes
    red_a[half][d] = se;
    red_b[half][d] = sw;
    __syncthreads();
    if (half == 0) {
        out[(size_t)b * DD + d] =
            (red_b[0][d] + red_b[1][d]) / (red_a[0][d] + red_a[1][d]);
    }
}

extern "C" void kernel_launch(void* const* d_in, const int* in_sizes, int n_in,
                              void* d_out, int out_size, void* d_ws, size_t ws_size,
                              hipStream_t stream) {
    const float* x   = (const float*)d_in[0];  // [B, D]
    const float* nbr = (const float*)d_in[1];  // [B, N, D]
    const float* W   = (const float*)d_in[2];  // [D, D]
    const float* A_w = (const float*)d_in[3];  // [2D, D]
    const float* A_b = (const float*)d_in[4];  // [D]
    float* out = (float*)d_out;                // [B, D]
    const int B = in_sizes[0] / DD;

    precompute_wa<<<dim3(DD, 2), DD, 0, stream>>>(W, A_w);
    attn_main<<<B, 256, 0, stream>>>(x, nbr, W, A_b, out);
}